// Round 3
// baseline (543.745 us; speedup 1.0000x reference)
//
#include <hip/hip_runtime.h>

typedef unsigned short u16;
typedef unsigned int   u32;

#define TPB 256

__device__ __forceinline__ float b2f(u16 u){ u32 x=((u32)u)<<16; return __uint_as_float(x); }
__device__ __forceinline__ u16 f2b(float f){ u32 x=__float_as_uint(f); u32 r=x+0x7FFFu+((x>>16)&1u); return (u16)(r>>16); }
__device__ __forceinline__ float lrelu(float x){ return x>0.f?x:0.2f*x; }
__device__ __forceinline__ float sigm(float x){ return 1.f/(1.f+__expf(-x)); }

// Load 4 consecutive float elements from either a bf16 or f32 array.
// i4 = element_offset/4 (element offset must be a multiple of 4).
__device__ __forceinline__ float4 ld4(const void* p, size_t i4, int isbf){
  if(isbf){
    ushort4 u=((const ushort4*)p)[i4];
    return make_float4(b2f(u.x),b2f(u.y),b2f(u.z),b2f(u.w));
  }
  return ((const float4*)p)[i4];
}

// ---------------- wire-dtype detection ----------------
// Interpret first 512 u16 words of W0 as bf16. bf16-wire: ~all have sane
// exponents for N(0,1/16) data. f32-wire: lo-halves are mantissa bits ->
// ~58% sane. Threshold 480/512.
__global__ void k_detect(const u16* __restrict__ w, int* __restrict__ flag){
  __shared__ int s[256];
  int t=threadIdx.x, sane=0;
  for(int i=t;i<512;i+=256){
    u16 u=w[i]; u32 e=(u>>7)&0xFFu;
    if((e>=103u&&e<=143u)||((u&0x7FFFu)==0u)) sane++;
  }
  s[t]=sane; __syncthreads();
  for(int o=128;o;o>>=1){ if(t<o) s[t]+=s[t+o]; __syncthreads(); }
  if(t==0) flag[0]=(s[0]>=480)?1:0;
}

// ---------------- graph build ----------------
__global__ void k_agent(const int* __restrict__ aidx, int* __restrict__ inv, int na, int N){
  int i=blockIdx.x*blockDim.x+threadIdx.x;
  if(i<na){ int a=aidx[i]; if(a>=0&&a<N) inv[a]=i; }
}

__global__ void k_deg(const int* __restrict__ dst, int E, int N, int* __restrict__ deg){
  int e=blockIdx.x*blockDim.x+threadIdx.x; if(e>=E+N) return;
  int d=(e<E)?dst[e]:(e-E);
  d=min(max(d,0),N-1);
  atomicAdd(&deg[d],1);
}

__global__ void k_scan(const int* __restrict__ deg, int* __restrict__ rs,
                       int* __restrict__ counter, int n){
  __shared__ int tmp[TPB];
  __shared__ int base;
  int i=blockIdx.x*TPB+threadIdx.x;
  int v=(i<n)?deg[i]:0;
  tmp[threadIdx.x]=v; __syncthreads();
  for(int off=1;off<TPB;off<<=1){
    int t=(threadIdx.x>=off)?tmp[threadIdx.x-off]:0;
    __syncthreads();
    tmp[threadIdx.x]+=t;
    __syncthreads();
  }
  if(threadIdx.x==TPB-1) base=atomicAdd(counter,tmp[TPB-1]);
  __syncthreads();
  if(i<n) rs[i]=base+tmp[threadIdx.x]-v;
}

__global__ void k_fill(const int* __restrict__ src, const int* __restrict__ dst, int E, int N,
                       const int* __restrict__ rs, int* __restrict__ fill, int* __restrict__ col){
  int e=blockIdx.x*blockDim.x+threadIdx.x; if(e>=E+N) return;
  int d,s;
  if(e<E){ d=dst[e]; s=src[e]; } else { d=e-E; s=e-E; }
  d=min(max(d,0),N-1); s=min(max(s,0),N-1);
  int p=rs[d]+atomicAdd(&fill[d],1);
  col[p]=s;
}

// ---------------- GEMM: C[M,256] = A[M,K] @ B[K,256]; C internal bf16 ----------------
// amode: 1 -> A is an internal bf16 buffer (h1); 0 -> A uses the wire dtype flag.
// B always uses the wire dtype flag (weights come from the harness).
__global__ __launch_bounds__(256) void k_gemm(const void* __restrict__ A, const void* __restrict__ B,
                                              u16* __restrict__ C, int M, int K,
                                              const int* __restrict__ flag, int amode){
  __shared__ __align__(16) float As[16][68];
  __shared__ __align__(16) float Bs[16][68];
  const int wire_isbf=flag[0];
  const int a_isbf = amode ? 1 : wire_isbf;
  const int t=threadIdx.x, tx=t&15, ty=t>>4;
  const int m0=blockIdx.x*64, n0=blockIdx.y*64;
  float acc[4][4]={};
  for(int k0=0;k0<K;k0+=16){
    { int r=t>>2, q=t&3, gm=m0+r;
      float4 u=make_float4(0.f,0.f,0.f,0.f);
      if(gm<M) u=ld4(A,((size_t)gm*K+k0+q*4)>>2,a_isbf);
      As[q*4+0][r]=u.x; As[q*4+1][r]=u.y;
      As[q*4+2][r]=u.z; As[q*4+3][r]=u.w;
    }
    { int r=t>>4, c=(t&15)*4;
      float4 u=ld4(B,((size_t)(k0+r)*256+n0+c)>>2,wire_isbf);
      Bs[r][c]=u.x; Bs[r][c+1]=u.y; Bs[r][c+2]=u.z; Bs[r][c+3]=u.w;
    }
    __syncthreads();
    #pragma unroll
    for(int k=0;k<16;++k){
      float4 a=*(const float4*)&As[k][ty*4];
      float4 b=*(const float4*)&Bs[k][tx*4];
      float av[4]={a.x,a.y,a.z,a.w}, bv[4]={b.x,b.y,b.z,b.w};
      #pragma unroll
      for(int i=0;i<4;++i)
        #pragma unroll
        for(int j=0;j<4;++j) acc[i][j]+=av[i]*bv[j];
    }
    __syncthreads();
  }
  #pragma unroll
  for(int i=0;i<4;++i){
    int gm=m0+ty*4+i;
    if(gm<M){
      ushort4 o; o.x=f2b(acc[i][0]); o.y=f2b(acc[i][1]); o.z=f2b(acc[i][2]); o.w=f2b(acc[i][3]);
      *(ushort4*)(C+(size_t)gm*256+n0+tx*4)=o;
    }
  }
}

// ---------------- attention logits per node (xl internal bf16) ----------------
__global__ __launch_bounds__(256) void k_att(const u16* __restrict__ xl, const void* __restrict__ as_,
                                             const void* __restrict__ ad_, float* __restrict__ asrc,
                                             float* __restrict__ adst, int n,
                                             const int* __restrict__ flag){
  const int isbf=flag[0];
  int w=(blockIdx.x*256+threadIdx.x)>>6;
  int lane=threadIdx.x&63;
  if(w>=n) return;
  int ch=lane*4;
  ushort4 u=*(const ushort4*)(xl+(size_t)w*256+ch);
  float4 s=ld4(as_,ch>>2,isbf);
  float4 d=ld4(ad_,ch>>2,isbf);
  float x0=b2f(u.x),x1=b2f(u.y),x2=b2f(u.z),x3=b2f(u.w);
  float ps=x0*s.x+x1*s.y+x2*s.z+x3*s.w;
  float pd=x0*d.x+x1*d.y+x2*d.z+x3*d.w;
  for(int off=16;off;off>>=1){ ps+=__shfl_xor(ps,off); pd+=__shfl_xor(pd,off); }
  if((lane&31)==0){ int h=lane>>5; asrc[w*2+h]=ps; adst[w*2+h]=pd; }
}

// ---------------- softmax + weighted aggregation, one wave per dst ----------------
__global__ __launch_bounds__(256) void k_agg(const int* __restrict__ rs, const int* __restrict__ deg,
    const int* __restrict__ col, const float* __restrict__ asrc, const float* __restrict__ adst,
    const u16* __restrict__ xl, const void* __restrict__ bias,
    u16* __restrict__ hout, void* __restrict__ out, int ostride, int ocol,
    const int* __restrict__ ainv, int n, const int* __restrict__ flag){
  const int isbf=flag[0];
  int w=(blockIdx.x*blockDim.x+threadIdx.x)>>6;
  int lane=threadIdx.x&63;
  if(w>=n) return;
  int s0=rs[w], cnt=deg[w];
  float ad0=adst[w*2], ad1=adst[w*2+1];
  int ch=lane*4, h=ch>>7;
  float4 acc=make_float4(0.f,0.f,0.f,0.f);
  float sum0=0.f, sum1=0.f;
  for(int base=0;base<cnt;base+=64){
    int j=base+lane;
    int sv=0; float w0=0.f, w1=0.f;
    if(j<cnt){
      sv=col[s0+j];
      w0=__expf(lrelu(asrc[sv*2]+ad0));
      w1=__expf(lrelu(asrc[sv*2+1]+ad1));
      sum0+=w0; sum1+=w1;
    }
    int rem=cnt-base; int lim=rem<64?rem:64;
    for(int tt=0;tt<lim;++tt){
      int   sb =__shfl(sv,tt);
      float w0b=__shfl(w0,tt);
      float w1b=__shfl(w1,tt);
      float wb = h ? w1b : w0b;
      ushort4 u=*(const ushort4*)(xl+(size_t)sb*256+ch);
      acc.x+=wb*b2f(u.x); acc.y+=wb*b2f(u.y); acc.z+=wb*b2f(u.z); acc.w+=wb*b2f(u.w);
    }
  }
  for(int off=32;off;off>>=1){ sum0+=__shfl_xor(sum0,off); sum1+=__shfl_xor(sum1,off); }
  float rh=1.f/((h?sum1:sum0)+1e-16f);
  float4 bv=ld4(bias,ch>>2,isbf);
  float r0=sigm(acc.x*rh+bv.x);
  float r1=sigm(acc.y*rh+bv.y);
  float r2=sigm(acc.z*rh+bv.z);
  float r3=sigm(acc.w*rh+bv.w);
  if(hout){
    ushort4 ov; ov.x=f2b(r0); ov.y=f2b(r1); ov.z=f2b(r2); ov.w=f2b(r3);
    *(ushort4*)(hout+(size_t)w*256+ch)=ov;
  }
  int ar=ainv[w];
  if(ar>=0){
    size_t o=(size_t)ar*ostride+ocol+ch;
    if(isbf){
      ushort4 ov; ov.x=f2b(r0); ov.y=f2b(r1); ov.z=f2b(r2); ov.w=f2b(r3);
      *(ushort4*)((u16*)out+o)=ov;
    }else{
      *(float4*)((float*)out+o)=make_float4(r0,r1,r2,r3);
    }
  }
}

extern "C" void kernel_launch(void* const* d_in, const int* in_sizes, int n_in,
                              void* d_out, int out_size, void* d_ws, size_t ws_size,
                              hipStream_t stream) {
  const void* x   = d_in[0];
  const int*  ei  = (const int*)d_in[1];
  const int*  aidx= (const int*)d_in[3];
  const void* W0  = d_in[4];
  const void* as0 = d_in[5];
  const void* ad0 = d_in[6];
  const void* b0  = d_in[7];
  const void* W1  = d_in[8];
  const void* as1 = d_in[9];
  const void* ad1 = d_in[10];
  const void* b1  = d_in[11];

  const int N  = in_sizes[0]/256;
  const int E  = in_sizes[1]/2;
  const int na = in_sizes[3];
  const int Et = E+N;

  char* ws=(char*)d_ws; size_t off=0;
  auto alloc=[&](size_t bytes)->void*{ void* p=ws+off; off+=(bytes+255)&~(size_t)255; return p; };
  int*   flg =(int*) alloc(256);
  u16*   xl  =(u16*) alloc((size_t)N*256*2);
  u16*   h1  =(u16*) alloc((size_t)N*256*2);
  float* asr =(float*)alloc((size_t)N*2*4);
  float* ads =(float*)alloc((size_t)N*2*4);
  int*   deg =(int*) alloc((size_t)N*4);
  int*   rstp=(int*) alloc((size_t)N*4);
  int*   fill=(int*) alloc((size_t)N*4);
  int*   ctr =(int*) alloc(256);
  int*   ainv=(int*) alloc((size_t)N*4);
  int*   col =(int*) alloc((size_t)Et*4);

  const int* esrc=ei;
  const int* edst=ei+E;

  hipMemsetAsync(deg ,0,(size_t)N*4,stream);
  hipMemsetAsync(fill,0,(size_t)N*4,stream);
  hipMemsetAsync(ctr ,0,256,stream);
  hipMemsetAsync(ainv,0xFF,(size_t)N*4,stream);

  k_detect<<<1,256,0,stream>>>((const u16*)W0,flg);
  k_agent<<<(na+255)/256,256,0,stream>>>(aidx,ainv,na,N);
  k_deg  <<<(Et+255)/256,256,0,stream>>>(edst,E,N,deg);
  k_scan <<<(N+TPB-1)/TPB,TPB,0,stream>>>(deg,rstp,ctr,N);
  k_fill <<<(Et+255)/256,256,0,stream>>>(esrc,edst,E,N,rstp,fill,col);

  dim3 gg((N+63)/64,4);
  // layer 0: A = x (wire dtype), B = W0 (wire dtype)
  k_gemm<<<gg,256,0,stream>>>(x,W0,xl,N,256,flg,0);
  k_att <<<(N+3)/4,256,0,stream>>>(xl,as0,ad0,asr,ads,N,flg);
  k_agg <<<(N+3)/4,256,0,stream>>>(rstp,deg,col,asr,ads,xl,b0,h1,d_out,512,0,ainv,N,flg);
  // layer 1: A = h1 (INTERNAL bf16 -> amode=1), B = W1 (wire dtype)
  k_gemm<<<gg,256,0,stream>>>(h1,W1,xl,N,256,flg,1);
  k_att <<<(N+3)/4,256,0,stream>>>(xl,as1,ad1,asr,ads,N,flg);
  k_agg <<<(N+3)/4,256,0,stream>>>(rstp,deg,col,asr,ads,xl,b1,(u16*)nullptr,d_out,512,256,ainv,N,flg);
}

// Round 4
// 443.590 us; speedup vs baseline: 1.2258x; 1.2258x over previous
//
#include <hip/hip_runtime.h>

typedef unsigned short u16;
typedef unsigned int   u32;
typedef __attribute__((ext_vector_type(8))) short short8;
typedef __attribute__((ext_vector_type(4))) float f32x4;

#define TPB 256

__device__ __forceinline__ float b2f(u16 u){ u32 x=((u32)u)<<16; return __uint_as_float(x); }
__device__ __forceinline__ u16 f2b(float f){ u32 x=__float_as_uint(f); u32 r=x+0x7FFFu+((x>>16)&1u); return (u16)(r>>16); }
__device__ __forceinline__ float lrelu(float x){ return x>0.f?x:0.2f*x; }
__device__ __forceinline__ float sigm(float x){ return 1.f/(1.f+__expf(-x)); }

__device__ __forceinline__ float4 ld4(const void* p, size_t i4, int isbf){
  if(isbf){
    ushort4 u=((const ushort4*)p)[i4];
    return make_float4(b2f(u.x),b2f(u.y),b2f(u.z),b2f(u.w));
  }
  return ((const float4*)p)[i4];
}
__device__ __forceinline__ float ld1(const void* p, size_t i, int isbf){
  return isbf ? b2f(((const u16*)p)[i]) : ((const float*)p)[i];
}

// ---------------- wire-dtype detection (flag=1 -> bf16 wire, 0 -> f32 wire) ----------------
__global__ void k_detect(const u16* __restrict__ w, int* __restrict__ flag){
  __shared__ int s[256];
  int t=threadIdx.x, sane=0;
  for(int i=t;i<512;i+=256){
    u16 u=w[i]; u32 e=(u>>7)&0xFFu;
    if((e>=103u&&e<=143u)||((u&0x7FFFu)==0u)) sane++;
  }
  s[t]=sane; __syncthreads();
  for(int o=128;o;o>>=1){ if(t<o) s[t]+=s[t+o]; __syncthreads(); }
  if(t==0) flag[0]=(s[0]>=480)?1:0;
}

// ---------------- graph build ----------------
__global__ void k_agent(const int* __restrict__ aidx, int* __restrict__ inv, int na, int N){
  int i=blockIdx.x*blockDim.x+threadIdx.x;
  if(i<na){ int a=aidx[i]; if(a>=0&&a<N) inv[a]=i; }
}

__global__ void k_deg(const int* __restrict__ dst, int E, int N, int* __restrict__ deg){
  int e=blockIdx.x*blockDim.x+threadIdx.x; if(e>=E+N) return;
  int d=(e<E)?dst[e]:(e-E);
  d=min(max(d,0),N-1);
  atomicAdd(&deg[d],1);
}

__global__ void k_scan(const int* __restrict__ deg, int* __restrict__ rs,
                       int* __restrict__ counter, int n){
  __shared__ int tmp[TPB];
  __shared__ int base;
  int i=blockIdx.x*TPB+threadIdx.x;
  int v=(i<n)?deg[i]:0;
  tmp[threadIdx.x]=v; __syncthreads();
  for(int off=1;off<TPB;off<<=1){
    int t=(threadIdx.x>=off)?tmp[threadIdx.x-off]:0;
    __syncthreads();
    tmp[threadIdx.x]+=t;
    __syncthreads();
  }
  if(threadIdx.x==TPB-1) base=atomicAdd(counter,tmp[TPB-1]);
  __syncthreads();
  if(i<n) rs[i]=base+tmp[threadIdx.x]-v;
}

__global__ void k_fill(const int* __restrict__ src, const int* __restrict__ dst, int E, int N,
                       const int* __restrict__ rs, int* __restrict__ fill, int* __restrict__ col){
  int e=blockIdx.x*blockDim.x+threadIdx.x; if(e>=E+N) return;
  int d,s;
  if(e<E){ d=dst[e]; s=src[e]; } else { d=e-E; s=e-E; }
  d=min(max(d,0),N-1); s=min(max(s,0),N-1);
  int p=rs[d]+atomicAdd(&fill[d],1);
  col[p]=s;
}

// ---------------- W[256,256] -> WT = W^T as bf16 ----------------
__global__ __launch_bounds__(256) void k_trans(const void* __restrict__ W, u16* __restrict__ WT,
                                               const int* __restrict__ flag){
  __shared__ float s[64][65];
  const int isbf=flag[0];
  int tx=threadIdx.x&63, ty=threadIdx.x>>6;
  int k0=blockIdx.x*64, n0=blockIdx.y*64;
  #pragma unroll
  for(int i=0;i<64;i+=4)
    s[ty+i][tx]=ld1(W,(size_t)(k0+ty+i)*256+n0+tx,isbf);
  __syncthreads();
  #pragma unroll
  for(int i=0;i<64;i+=4)
    WT[(size_t)(n0+ty+i)*256+k0+tx]=f2b(s[tx][ty+i]);
}

// ---------------- MFMA GEMM: C[M,256] = A[M,256] @ B[256,256], BT = B^T bf16 ----------------
// amode: 1 -> A internal bf16; 0 -> A wire dtype (f32 converted inline, or bf16).
__global__ __launch_bounds__(256) void k_gemm(const void* __restrict__ A, const u16* __restrict__ BT,
                                              u16* __restrict__ C, int M,
                                              const int* __restrict__ flag, int amode){
  __shared__ short As[128*32];
  __shared__ short Bs[128*32];
  const int a_isbf = amode ? 1 : flag[0];
  const int t=threadIdx.x;
  const int lane=t&63, wv=t>>6;
  const int wm=wv>>1, wn=wv&1;
  const int m15=lane&15, kg=lane>>4;
  const int gm0=blockIdx.x*128, n0=blockIdx.y*128;
  f32x4 acc[4][4]={};
  for(int k0=0;k0<256;k0+=32){
    #pragma unroll
    for(int i=0;i<2;++i){
      int c=i*256+t;
      int r=c>>2, kq=c&3;
      int sw=(kq^((r>>1)&3))*8;
      // A chunk: row gm0+r (clamped), elems k0+kq*8 .. +8
      int gr=gm0+r; gr=gr<M?gr:M-1;
      size_t ge=(size_t)gr*256+k0+kq*8;
      short8 av;
      if(a_isbf){
        av=*(const short8*)((const u16*)A+ge);
      }else{
        const float4* fp=(const float4*)((const float*)A+ge);
        float4 f0=fp[0], f1=fp[1];
        av[0]=(short)f2b(f0.x); av[1]=(short)f2b(f0.y); av[2]=(short)f2b(f0.z); av[3]=(short)f2b(f0.w);
        av[4]=(short)f2b(f1.x); av[5]=(short)f2b(f1.y); av[6]=(short)f2b(f1.z); av[7]=(short)f2b(f1.w);
      }
      *(short8*)&As[r*32+sw]=av;
      // B chunk: BT row n0+r (always <256)
      short8 bv=*(const short8*)(BT+(size_t)(n0+r)*256+k0+kq*8);
      *(short8*)&Bs[r*32+sw]=bv;
    }
    __syncthreads();
    short8 af[4], bf[4];
    #pragma unroll
    for(int mi=0;mi<4;++mi){
      int row=wm*64+mi*16+m15;
      af[mi]=*(const short8*)&As[row*32+((kg^((row>>1)&3)))*8];
    }
    #pragma unroll
    for(int ni=0;ni<4;++ni){
      int row=wn*64+ni*16+m15;
      bf[ni]=*(const short8*)&Bs[row*32+((kg^((row>>1)&3)))*8];
    }
    #pragma unroll
    for(int mi=0;mi<4;++mi)
      #pragma unroll
      for(int ni=0;ni<4;++ni)
        acc[mi][ni]=__builtin_amdgcn_mfma_f32_16x16x32_bf16(af[mi],bf[ni],acc[mi][ni],0,0,0);
    __syncthreads();
  }
  #pragma unroll
  for(int mi=0;mi<4;++mi){
    #pragma unroll
    for(int r=0;r<4;++r){
      int grow=gm0+wm*64+mi*16+kg*4+r;
      if(grow<M){
        #pragma unroll
        for(int ni=0;ni<4;++ni){
          int gcol=n0+wn*64+ni*16+m15;
          C[(size_t)grow*256+gcol]=f2b(acc[mi][ni][r]);
        }
      }
    }
  }
}

// ---------------- attention logits per node (xl internal bf16) ----------------
__global__ __launch_bounds__(256) void k_att(const u16* __restrict__ xl, const void* __restrict__ as_,
                                             const void* __restrict__ ad_, float* __restrict__ asrc,
                                             float* __restrict__ adst, int n,
                                             const int* __restrict__ flag){
  const int isbf=flag[0];
  int w=(blockIdx.x*256+threadIdx.x)>>6;
  int lane=threadIdx.x&63;
  if(w>=n) return;
  int ch=lane*4;
  ushort4 u=*(const ushort4*)(xl+(size_t)w*256+ch);
  float4 s=ld4(as_,ch>>2,isbf);
  float4 d=ld4(ad_,ch>>2,isbf);
  float x0=b2f(u.x),x1=b2f(u.y),x2=b2f(u.z),x3=b2f(u.w);
  float ps=x0*s.x+x1*s.y+x2*s.z+x3*s.w;
  float pd=x0*d.x+x1*d.y+x2*d.z+x3*d.w;
  for(int off=16;off;off>>=1){ ps+=__shfl_xor(ps,off); pd+=__shfl_xor(pd,off); }
  if((lane&31)==0){ int h=lane>>5; asrc[w*2+h]=ps; adst[w*2+h]=pd; }
}

// ---------------- softmax + weighted aggregation, one wave per dst ----------------
__global__ __launch_bounds__(256) void k_agg(const int* __restrict__ rs, const int* __restrict__ deg,
    const int* __restrict__ col, const float* __restrict__ asrc, const float* __restrict__ adst,
    const u16* __restrict__ xl, const void* __restrict__ bias,
    u16* __restrict__ hout, void* __restrict__ out, int ostride, int ocol,
    const int* __restrict__ ainv, int n, const int* __restrict__ flag){
  const int isbf=flag[0];
  int w=(blockIdx.x*blockDim.x+threadIdx.x)>>6;
  int lane=threadIdx.x&63;
  if(w>=n) return;
  int s0=rs[w], cnt=deg[w];
  float ad0=adst[w*2], ad1=adst[w*2+1];
  int ch=lane*4, h=ch>>7;
  float4 acc=make_float4(0.f,0.f,0.f,0.f);
  float sum0=0.f, sum1=0.f;
  for(int base=0;base<cnt;base+=64){
    int j=base+lane;
    int sv=0; float w0=0.f, w1=0.f;
    if(j<cnt){
      sv=col[s0+j];
      w0=__expf(lrelu(asrc[sv*2]+ad0));
      w1=__expf(lrelu(asrc[sv*2+1]+ad1));
      sum0+=w0; sum1+=w1;
    }
    int rem=cnt-base; int lim=rem<64?rem:64;
    for(int tt=0;tt<lim;++tt){
      int   sb =__shfl(sv,tt);
      float w0b=__shfl(w0,tt);
      float w1b=__shfl(w1,tt);
      float wb = h ? w1b : w0b;
      ushort4 u=*(const ushort4*)(xl+(size_t)sb*256+ch);
      acc.x+=wb*b2f(u.x); acc.y+=wb*b2f(u.y); acc.z+=wb*b2f(u.z); acc.w+=wb*b2f(u.w);
    }
  }
  for(int off=32;off;off>>=1){ sum0+=__shfl_xor(sum0,off); sum1+=__shfl_xor(sum1,off); }
  float rh=1.f/((h?sum1:sum0)+1e-16f);
  float4 bv=ld4(bias,ch>>2,isbf);
  float r0=sigm(acc.x*rh+bv.x);
  float r1=sigm(acc.y*rh+bv.y);
  float r2=sigm(acc.z*rh+bv.z);
  float r3=sigm(acc.w*rh+bv.w);
  if(hout){
    ushort4 ov; ov.x=f2b(r0); ov.y=f2b(r1); ov.z=f2b(r2); ov.w=f2b(r3);
    *(ushort4*)(hout+(size_t)w*256+ch)=ov;
  }
  int ar=ainv[w];
  if(ar>=0){
    size_t o=(size_t)ar*ostride+ocol+ch;
    if(isbf){
      ushort4 ov; ov.x=f2b(r0); ov.y=f2b(r1); ov.z=f2b(r2); ov.w=f2b(r3);
      *(ushort4*)((u16*)out+o)=ov;
    }else{
      *(float4*)((float*)out+o)=make_float4(r0,r1,r2,r3);
    }
  }
}

extern "C" void kernel_launch(void* const* d_in, const int* in_sizes, int n_in,
                              void* d_out, int out_size, void* d_ws, size_t ws_size,
                              hipStream_t stream) {
  const void* x   = d_in[0];
  const int*  ei  = (const int*)d_in[1];
  const int*  aidx= (const int*)d_in[3];
  const void* W0  = d_in[4];
  const void* as0 = d_in[5];
  const void* ad0 = d_in[6];
  const void* b0  = d_in[7];
  const void* W1  = d_in[8];
  const void* as1 = d_in[9];
  const void* ad1 = d_in[10];
  const void* b1  = d_in[11];

  const int N  = in_sizes[0]/256;
  const int E  = in_sizes[1]/2;
  const int na = in_sizes[3];
  const int Et = E+N;

  char* ws=(char*)d_ws; size_t off=0;
  auto alloc=[&](size_t bytes)->void*{ void* p=ws+off; off+=(bytes+255)&~(size_t)255; return p; };
  int*   flg =(int*) alloc(256);
  u16*   xl  =(u16*) alloc((size_t)N*256*2);
  u16*   h1  =(u16*) alloc((size_t)N*256*2);
  u16*   WT0 =(u16*) alloc((size_t)256*256*2);
  u16*   WT1 =(u16*) alloc((size_t)256*256*2);
  float* asr =(float*)alloc((size_t)N*2*4);
  float* ads =(float*)alloc((size_t)N*2*4);
  int*   deg =(int*) alloc((size_t)N*4);
  int*   rstp=(int*) alloc((size_t)N*4);
  int*   fill=(int*) alloc((size_t)N*4);
  int*   ctr =(int*) alloc(256);
  int*   ainv=(int*) alloc((size_t)N*4);
  int*   col =(int*) alloc((size_t)Et*4);

  const int* esrc=ei;
  const int* edst=ei+E;

  hipMemsetAsync(deg ,0,(size_t)N*4,stream);
  hipMemsetAsync(fill,0,(size_t)N*4,stream);
  hipMemsetAsync(ctr ,0,256,stream);
  hipMemsetAsync(ainv,0xFF,(size_t)N*4,stream);

  k_detect<<<1,256,0,stream>>>((const u16*)W0,flg);
  k_agent<<<(na+255)/256,256,0,stream>>>(aidx,ainv,na,N);
  k_deg  <<<(Et+255)/256,256,0,stream>>>(edst,E,N,deg);
  k_scan <<<(N+TPB-1)/TPB,TPB,0,stream>>>(deg,rstp,ctr,N);
  k_fill <<<(Et+255)/256,256,0,stream>>>(esrc,edst,E,N,rstp,fill,col);

  dim3 gt(4,4);
  k_trans<<<gt,256,0,stream>>>(W0,WT0,flg);
  k_trans<<<gt,256,0,stream>>>(W1,WT1,flg);

  dim3 gg((N+127)/128,2);
  // layer 0: A = x (wire dtype), B^T = WT0
  k_gemm<<<gg,256,0,stream>>>(x,WT0,xl,N,flg,0);
  k_att <<<(N+3)/4,256,0,stream>>>(xl,as0,ad0,asr,ads,N,flg);
  k_agg <<<(N+3)/4,256,0,stream>>>(rstp,deg,col,asr,ads,xl,b0,h1,d_out,512,0,ainv,N,flg);
  // layer 1: A = h1 (internal bf16), B^T = WT1
  k_gemm<<<gg,256,0,stream>>>(h1,WT1,xl,N,flg,1);
  k_att <<<(N+3)/4,256,0,stream>>>(xl,as1,ad1,asr,ads,N,flg);
  k_agg <<<(N+3)/4,256,0,stream>>>(rstp,deg,col,asr,ads,xl,b1,(u16*)nullptr,d_out,512,256,ainv,N,flg);
}

// Round 5
// 434.111 us; speedup vs baseline: 1.2525x; 1.0218x over previous
//
#include <hip/hip_runtime.h>
#include <hip/hip_fp16.h>

typedef unsigned short u16;
typedef unsigned int   u32;
typedef __attribute__((ext_vector_type(8))) short short8;
typedef __attribute__((ext_vector_type(4))) float f32x4;

#define TPB 256

__device__ __forceinline__ float b2f(u16 u){ u32 x=((u32)u)<<16; return __uint_as_float(x); }
__device__ __forceinline__ u16 f2b(float f){ u32 x=__float_as_uint(f); u32 r=x+0x7FFFu+((x>>16)&1u); return (u16)(r>>16); }
__device__ __forceinline__ float lrelu(float x){ return x>0.f?x:0.2f*x; }
__device__ __forceinline__ float sigm(float x){ return 1.f/(1.f+__expf(-x)); }

__device__ __forceinline__ float4 ld4(const void* p, size_t i4, int isbf){
  if(isbf){
    ushort4 u=((const ushort4*)p)[i4];
    return make_float4(b2f(u.x),b2f(u.y),b2f(u.z),b2f(u.w));
  }
  return ((const float4*)p)[i4];
}
__device__ __forceinline__ float ld1(const void* p, size_t i, int isbf){
  return isbf ? b2f(((const u16*)p)[i]) : ((const float*)p)[i];
}

// ---------------- wire-dtype detection (flag=1 -> bf16 wire, 0 -> f32 wire) ----------------
__global__ void k_detect(const u16* __restrict__ w, int* __restrict__ flag){
  __shared__ int s[256];
  int t=threadIdx.x, sane=0;
  for(int i=t;i<512;i+=256){
    u16 u=w[i]; u32 e=(u>>7)&0xFFu;
    if((e>=103u&&e<=143u)||((u&0x7FFFu)==0u)) sane++;
  }
  s[t]=sane; __syncthreads();
  for(int o=128;o;o>>=1){ if(t<o) s[t]+=s[t+o]; __syncthreads(); }
  if(t==0) flag[0]=(s[0]>=480)?1:0;
}

// ---------------- graph build ----------------
__global__ void k_deg(const int* __restrict__ dst, int E, int N, int* __restrict__ deg){
  int e=blockIdx.x*blockDim.x+threadIdx.x; if(e>=E+N) return;
  int d=(e<E)?dst[e]:(e-E);
  d=min(max(d,0),N-1);
  atomicAdd(&deg[d],1);
}

// block-scan prefix sum + agent inverse-map scatter (ainv pre-memset to -1)
__global__ void k_scan(const int* __restrict__ deg, int* __restrict__ rs,
                       int* __restrict__ counter, int n,
                       const int* __restrict__ aidx, int* __restrict__ ainv, int na){
  __shared__ int tmp[TPB];
  __shared__ int base;
  int i=blockIdx.x*TPB+threadIdx.x;
  if(i<na){ int a=aidx[i]; if(a>=0&&a<n) ainv[a]=i; }
  int v=(i<n)?deg[i]:0;
  tmp[threadIdx.x]=v; __syncthreads();
  for(int off=1;off<TPB;off<<=1){
    int t=(threadIdx.x>=off)?tmp[threadIdx.x-off]:0;
    __syncthreads();
    tmp[threadIdx.x]+=t;
    __syncthreads();
  }
  if(threadIdx.x==TPB-1) base=atomicAdd(counter,tmp[TPB-1]);
  __syncthreads();
  if(i<n) rs[i]=base+tmp[threadIdx.x]-v;
}

__global__ void k_fill(const int* __restrict__ src, const int* __restrict__ dst, int E, int N,
                       const int* __restrict__ rs, int* __restrict__ fill, int* __restrict__ col){
  int e=blockIdx.x*blockDim.x+threadIdx.x; if(e>=E+N) return;
  int d,s;
  if(e<E){ d=dst[e]; s=src[e]; } else { d=e-E; s=e-E; }
  d=min(max(d,0),N-1); s=min(max(s,0),N-1);
  int p=rs[d]+atomicAdd(&fill[d],1);
  col[p]=s;
}

// ---------------- W[256,256] -> WT = W^T as bf16 (z selects which weight) ----------------
__global__ __launch_bounds__(256) void k_trans(const void* __restrict__ Wa, u16* __restrict__ WTa,
                                               const void* __restrict__ Wb, u16* __restrict__ WTb,
                                               const int* __restrict__ flag){
  __shared__ float s[64][65];
  const void* W = blockIdx.z ? Wb : Wa;
  u16* WT = blockIdx.z ? WTb : WTa;
  const int isbf=flag[0];
  int tx=threadIdx.x&63, ty=threadIdx.x>>6;
  int k0=blockIdx.x*64, n0=blockIdx.y*64;
  #pragma unroll
  for(int i=0;i<64;i+=4)
    s[ty+i][tx]=ld1(W,(size_t)(k0+ty+i)*256+n0+tx,isbf);
  __syncthreads();
  #pragma unroll
  for(int i=0;i<64;i+=4)
    WT[(size_t)(n0+ty+i)*256+k0+tx]=f2b(s[tx][ty+i]);
}

// ---------------- MFMA GEMM: C[M,256] = A[M,256] @ B[256,256], BT = B^T bf16 ----------------
__global__ __launch_bounds__(256) void k_gemm(const void* __restrict__ A, const u16* __restrict__ BT,
                                              u16* __restrict__ C, int M,
                                              const int* __restrict__ flag, int amode){
  __shared__ short As[128*32];
  __shared__ short Bs[128*32];
  const int a_isbf = amode ? 1 : flag[0];
  const int t=threadIdx.x;
  const int lane=t&63, wv=t>>6;
  const int wm=wv>>1, wn=wv&1;
  const int m15=lane&15, kg=lane>>4;
  const int gm0=blockIdx.x*128, n0=blockIdx.y*128;
  f32x4 acc[4][4]={};
  for(int k0=0;k0<256;k0+=32){
    #pragma unroll
    for(int i=0;i<2;++i){
      int c=i*256+t;
      int r=c>>2, kq=c&3;
      int sw=(kq^((r>>1)&3))*8;
      int gr=gm0+r; gr=gr<M?gr:M-1;
      size_t ge=(size_t)gr*256+k0+kq*8;
      short8 av;
      if(a_isbf){
        av=*(const short8*)((const u16*)A+ge);
      }else{
        const float4* fp=(const float4*)((const float*)A+ge);
        float4 f0=fp[0], f1=fp[1];
        av[0]=(short)f2b(f0.x); av[1]=(short)f2b(f0.y); av[2]=(short)f2b(f0.z); av[3]=(short)f2b(f0.w);
        av[4]=(short)f2b(f1.x); av[5]=(short)f2b(f1.y); av[6]=(short)f2b(f1.z); av[7]=(short)f2b(f1.w);
      }
      *(short8*)&As[r*32+sw]=av;
      short8 bv=*(const short8*)(BT+(size_t)(n0+r)*256+k0+kq*8);
      *(short8*)&Bs[r*32+sw]=bv;
    }
    __syncthreads();
    short8 af[4], bf[4];
    #pragma unroll
    for(int mi=0;mi<4;++mi){
      int row=wm*64+mi*16+m15;
      af[mi]=*(const short8*)&As[row*32+((kg^((row>>1)&3)))*8];
    }
    #pragma unroll
    for(int ni=0;ni<4;++ni){
      int row=wn*64+ni*16+m15;
      bf[ni]=*(const short8*)&Bs[row*32+((kg^((row>>1)&3)))*8];
    }
    #pragma unroll
    for(int mi=0;mi<4;++mi)
      #pragma unroll
      for(int ni=0;ni<4;++ni)
        acc[mi][ni]=__builtin_amdgcn_mfma_f32_16x16x32_bf16(af[mi],bf[ni],acc[mi][ni],0,0,0);
    __syncthreads();
  }
  #pragma unroll
  for(int mi=0;mi<4;++mi){
    #pragma unroll
    for(int r=0;r<4;++r){
      int grow=gm0+wm*64+mi*16+kg*4+r;
      if(grow<M){
        #pragma unroll
        for(int ni=0;ni<4;++ni){
          int gcol=n0+wn*64+ni*16+m15;
          C[(size_t)grow*256+gcol]=f2b(acc[mi][ni][r]);
        }
      }
    }
  }
}

// ---------------- attention logits per node (xl internal bf16) ----------------
__global__ __launch_bounds__(256) void k_att(const u16* __restrict__ xl, const void* __restrict__ as_,
                                             const void* __restrict__ ad_, float* __restrict__ asrc,
                                             float* __restrict__ adst, int n,
                                             const int* __restrict__ flag){
  const int isbf=flag[0];
  int w=(blockIdx.x*256+threadIdx.x)>>6;
  int lane=threadIdx.x&63;
  if(w>=n) return;
  int ch=lane*4;
  ushort4 u=*(const ushort4*)(xl+(size_t)w*256+ch);
  float4 s=ld4(as_,ch>>2,isbf);
  float4 d=ld4(ad_,ch>>2,isbf);
  float x0=b2f(u.x),x1=b2f(u.y),x2=b2f(u.z),x3=b2f(u.w);
  float ps=x0*s.x+x1*s.y+x2*s.z+x3*s.w;
  float pd=x0*d.x+x1*d.y+x2*d.z+x3*d.w;
  for(int off=16;off;off>>=1){ ps+=__shfl_xor(ps,off); pd+=__shfl_xor(pd,off); }
  if((lane&31)==0){ int h=lane>>5; asrc[w*2+h]=ps; adst[w*2+h]=pd; }
}

// ---------------- per-edge softmax weights + per-dst denominators ----------------
__global__ __launch_bounds__(256) void k_alpha(const int* __restrict__ rs, const int* __restrict__ deg,
    const int* __restrict__ col, const float2* __restrict__ asrc2, const float2* __restrict__ adst2,
    u32* __restrict__ wpk, float2* __restrict__ rden, int n){
  int w=(blockIdx.x*256+threadIdx.x)>>6;
  int lane=threadIdx.x&63;
  if(w>=n) return;
  int s0=rs[w], cnt=deg[w];
  float2 ad=adst2[w];
  float sum0=0.f, sum1=0.f;
  for(int base=0;base<cnt;base+=64){
    int j=base+lane;
    if(j<cnt){
      int sv=col[s0+j];
      float2 a=asrc2[sv];
      float e0=fminf(lrelu(a.x+ad.x),11.f);   // clamp: keep exp finite in f16
      float e1=fminf(lrelu(a.y+ad.y),11.f);
      float w0=__expf(e0), w1=__expf(e1);
      sum0+=w0; sum1+=w1;
      __half2 p=__floats2half2_rn(w0,w1);
      wpk[s0+j]=*(u32*)&p;
    }
  }
  for(int off=32;off;off>>=1){ sum0+=__shfl_xor(sum0,off); sum1+=__shfl_xor(sum1,off); }
  if(lane==0) rden[w]=make_float2(1.f/(sum0+1e-16f),1.f/(sum1+1e-16f));
}

// ---------------- weighted aggregation: wave per dst, no cross-lane ops ----------------
__global__ __launch_bounds__(256) void k_agg(const int* __restrict__ rs, const int* __restrict__ deg,
    const int* __restrict__ col, const u32* __restrict__ wpk, const float2* __restrict__ rden,
    const u16* __restrict__ xl, const void* __restrict__ bias,
    u16* __restrict__ hout, void* __restrict__ out, int ostride, int ocol,
    const int* __restrict__ ainv, int n, const int* __restrict__ flag){
  const int isbf=flag[0];
  int w=(blockIdx.x*blockDim.x+threadIdx.x)>>6;
  int lane=threadIdx.x&63;
  if(w>=n) return;
  int s0=rs[w], cnt=deg[w];
  int ch=lane*4, h=ch>>7;
  float4 acc=make_float4(0.f,0.f,0.f,0.f);
  int j=0;
  for(; j+4<=cnt; j+=4){
    int sb[4]; u32 ap[4];
    #pragma unroll
    for(int u=0;u<4;++u){ sb[u]=col[s0+j+u]; ap[u]=wpk[s0+j+u]; }
    ushort4 r[4];
    #pragma unroll
    for(int u=0;u<4;++u) r[u]=*(const ushort4*)(xl+(size_t)sb[u]*256+ch);
    #pragma unroll
    for(int u=0;u<4;++u){
      __half2 p=*(__half2*)&ap[u];
      float wb=__half2float(h?__high2half(p):__low2half(p));
      acc.x+=wb*b2f(r[u].x); acc.y+=wb*b2f(r[u].y);
      acc.z+=wb*b2f(r[u].z); acc.w+=wb*b2f(r[u].w);
    }
  }
  for(; j<cnt; ++j){
    int sb=col[s0+j]; u32 ap=wpk[s0+j];
    ushort4 r=*(const ushort4*)(xl+(size_t)sb*256+ch);
    __half2 p=*(__half2*)&ap;
    float wb=__half2float(h?__high2half(p):__low2half(p));
    acc.x+=wb*b2f(r.x); acc.y+=wb*b2f(r.y);
    acc.z+=wb*b2f(r.z); acc.w+=wb*b2f(r.w);
  }
  float2 rd=rden[w];
  float rh=h?rd.y:rd.x;
  float4 bv=ld4(bias,ch>>2,isbf);
  float r0=sigm(acc.x*rh+bv.x);
  float r1=sigm(acc.y*rh+bv.y);
  float r2=sigm(acc.z*rh+bv.z);
  float r3=sigm(acc.w*rh+bv.w);
  if(hout){
    ushort4 ov; ov.x=f2b(r0); ov.y=f2b(r1); ov.z=f2b(r2); ov.w=f2b(r3);
    *(ushort4*)(hout+(size_t)w*256+ch)=ov;
  }
  int ar=ainv[w];
  if(ar>=0){
    size_t o=(size_t)ar*ostride+ocol+ch;
    if(isbf){
      ushort4 ov; ov.x=f2b(r0); ov.y=f2b(r1); ov.z=f2b(r2); ov.w=f2b(r3);
      *(ushort4*)((u16*)out+o)=ov;
    }else{
      *(float4*)((float*)out+o)=make_float4(r0,r1,r2,r3);
    }
  }
}

extern "C" void kernel_launch(void* const* d_in, const int* in_sizes, int n_in,
                              void* d_out, int out_size, void* d_ws, size_t ws_size,
                              hipStream_t stream) {
  const void* x   = d_in[0];
  const int*  ei  = (const int*)d_in[1];
  const int*  aidx= (const int*)d_in[3];
  const void* W0  = d_in[4];
  const void* as0 = d_in[5];
  const void* ad0 = d_in[6];
  const void* b0  = d_in[7];
  const void* W1  = d_in[8];
  const void* as1 = d_in[9];
  const void* ad1 = d_in[10];
  const void* b1  = d_in[11];

  const int N  = in_sizes[0]/256;
  const int E  = in_sizes[1]/2;
  const int na = in_sizes[3];
  const int Et = E+N;

  char* ws=(char*)d_ws; size_t off=0;
  auto alloc=[&](size_t bytes)->void*{ void* p=ws+off; off+=(bytes+255)&~(size_t)255; return p; };
  int*   flg =(int*) alloc(256);
  u16*   xl  =(u16*) alloc((size_t)N*256*2);
  u16*   h1  =(u16*) alloc((size_t)N*256*2);
  u16*   WT0 =(u16*) alloc((size_t)256*256*2);
  u16*   WT1 =(u16*) alloc((size_t)256*256*2);
  float* asr =(float*)alloc((size_t)N*2*4);
  float* ads =(float*)alloc((size_t)N*2*4);
  // zero-init region: deg, fill, ctr contiguous -> one memset
  char*  zbase=ws+off;
  int*   deg =(int*) alloc((size_t)N*4);
  int*   fill=(int*) alloc((size_t)N*4);
  int*   ctr =(int*) alloc(256);
  size_t zlen=(ws+off)-zbase;
  int*   rstp=(int*) alloc((size_t)N*4);
  int*   ainv=(int*) alloc((size_t)N*4);
  int*   col =(int*) alloc((size_t)Et*4);
  u32*   wpk =(u32*) alloc((size_t)Et*4);
  float2* rdn=(float2*)alloc((size_t)N*8);

  const int* esrc=ei;
  const int* edst=ei+E;

  hipMemsetAsync(zbase,0,zlen,stream);
  hipMemsetAsync(ainv,0xFF,(size_t)N*4,stream);

  k_detect<<<1,256,0,stream>>>((const u16*)W0,flg);
  k_deg  <<<(Et+255)/256,256,0,stream>>>(edst,E,N,deg);
  k_scan <<<(N+TPB-1)/TPB,TPB,0,stream>>>(deg,rstp,ctr,N,aidx,ainv,na);
  k_fill <<<(Et+255)/256,256,0,stream>>>(esrc,edst,E,N,rstp,fill,col);
  k_trans<<<dim3(4,4,2),256,0,stream>>>(W0,WT0,W1,WT1,flg);

  dim3 gg((N+127)/128,2);
  // layer 0
  k_gemm <<<gg,256,0,stream>>>(x,WT0,xl,N,flg,0);
  k_att  <<<(N+3)/4,256,0,stream>>>(xl,as0,ad0,asr,ads,N,flg);
  k_alpha<<<(N+3)/4,256,0,stream>>>(rstp,deg,col,(const float2*)asr,(const float2*)ads,wpk,rdn,N);
  k_agg  <<<(N+3)/4,256,0,stream>>>(rstp,deg,col,wpk,rdn,xl,b0,h1,d_out,512,0,ainv,N,flg);
  // layer 1
  k_gemm <<<gg,256,0,stream>>>(h1,WT1,xl,N,flg,1);
  k_att  <<<(N+3)/4,256,0,stream>>>(xl,as1,ad1,asr,ads,N,flg);
  k_alpha<<<(N+3)/4,256,0,stream>>>(rstp,deg,col,(const float2*)asr,(const float2*)ads,wpk,rdn,N);
  k_agg  <<<(N+3)/4,256,0,stream>>>(rstp,deg,col,wpk,rdn,xl,b1,(u16*)nullptr,d_out,512,256,ainv,N,flg);
}